// Round 2
// baseline (487.676 us; speedup 1.0000x reference)
//
#include <hip/hip_runtime.h>

#define F_EDGE 8
#define H 8

__device__ __forceinline__ unsigned short f2bf(float f) {
    unsigned u = __float_as_uint(f);
    unsigned r = u + 0x7fffu + ((u >> 16) & 1u);
    return (unsigned short)(r >> 16);
}
__device__ __forceinline__ float bflo(unsigned u) { return __uint_as_float(u << 16); }
__device__ __forceinline__ float bfhi(unsigned u) { return __uint_as_float(u & 0xffff0000u); }

// ---------------- CSR build (once, amortized over both edge passes) ---------

__global__ __launch_bounds__(256) void zero_kernel(int* __restrict__ p, int n) {
    int i = blockIdx.x * 256 + threadIdx.x;
    if (i < n) p[i] = 0;
}

__global__ __launch_bounds__(256) void degree_kernel(const int* __restrict__ ei,
                                                     int* __restrict__ deg, int E) {
    int e = blockIdx.x * 256 + threadIdx.x;
    if (e < E) atomicAdd(&deg[ei[E + e]], 1);
}

// Single-block exclusive scan over deg[0..n) -> off[0..n], also copies to cursor.
__global__ __launch_bounds__(1024) void scan_kernel(const int* __restrict__ deg,
                                                    int* __restrict__ off,
                                                    int* __restrict__ cursor, int n) {
    __shared__ int s[1024];
    int t = threadIdx.x;
    int C = (n + 1023) >> 10;
    int base = t * C;
    int sum = 0;
    for (int i = 0; i < C; ++i) {
        int idx = base + i;
        if (idx < n) sum += deg[idx];
    }
    s[t] = sum;
    __syncthreads();
    for (int d = 1; d < 1024; d <<= 1) {
        int v = (t >= d) ? s[t - d] : 0;
        __syncthreads();
        s[t] += v;
        __syncthreads();
    }
    int run = (t == 0) ? 0 : s[t - 1];
    for (int i = 0; i < C; ++i) {
        int idx = base + i;
        if (idx < n) {
            off[idx] = run;
            cursor[idx] = run;
            run += deg[idx];
        }
    }
    if (t == 1023) off[n] = s[1023];
}

__global__ __launch_bounds__(256) void scatter_kernel(const int* __restrict__ ei,
                                                      int* __restrict__ cursor,
                                                      int2* __restrict__ sorted, int E) {
    int e = blockIdx.x * 256 + threadIdx.x;
    if (e < E) {
        int s_ = ei[e];
        int d_ = ei[E + e];
        int pos = atomicAdd(&cursor[d_], 1);
        sorted[pos] = make_int2(s_, e);
    }
}

// ---------------- Per-node precompute (unchanged) ---------------------------
//   Pt[n][j][k]   = sum_i feat[n][i] * We[k][i*H+j]   (stored bf16)
//   q[n][j]       = sum_i feat[n][i] * be[i*H+j]
//   aggseed[n][j] = b[j] + sum_i feat[n][i] * root[i*H+j]
template <int IN, bool RELU, bool INIT>
__global__ __launch_bounds__(256) void prep_kernel(
    const float* __restrict__ feat, const float* __restrict__ We,
    const float* __restrict__ be, const float* __restrict__ root,
    const float* __restrict__ b, unsigned short* __restrict__ Pt,
    float* __restrict__ q, float* __restrict__ aggseed, int n_nodes,
    float* __restrict__ out, const float* __restrict__ blast, int out_n) {
    __shared__ float sW[IN * H * 12];
    int tid = threadIdx.x;
    for (int t = tid; t < IN * H * 12; t += 256) {
        int r = t / 12, m = t - r * 12;   // r = i*H + j
        float v = 0.f;
        if (m < 8) v = We[m * (IN * H) + r];
        else if (m == 8) v = be[r];
        else if (m == 9) v = root[r];
        sW[t] = v;
    }
    if (INIT && blockIdx.x == 0) {
        float bl = blast[0];
        for (int t = tid; t < out_n; t += 256) out[t] = bl;
    }
    __syncthreads();

    int n = blockIdx.x * 32 + (tid >> 3);
    if (n >= n_nodes) return;
    int j = tid & 7;

    float f[IN];
    const float4* fv = (const float4*)(feat + (long long)n * IN);
#pragma unroll
    for (int i4 = 0; i4 < IN / 4; ++i4) {
        float4 v = fv[i4];
        f[i4 * 4 + 0] = v.x; f[i4 * 4 + 1] = v.y;
        f[i4 * 4 + 2] = v.z; f[i4 * 4 + 3] = v.w;
    }
    if (RELU) {
#pragma unroll
        for (int i = 0; i < IN; ++i) f[i] = f[i] > 0.f ? f[i] : 0.f;
    }

    float p[8] = {0.f, 0.f, 0.f, 0.f, 0.f, 0.f, 0.f, 0.f};
    float qq = 0.f, hr = 0.f;
#pragma unroll
    for (int i = 0; i < IN; ++i) {
        const float* row = &sW[(i * 8 + j) * 12];
        float4 w0 = *(const float4*)row;
        float4 w1 = *(const float4*)(row + 4);
        float2 br = *(const float2*)(row + 8);
        float fi = f[i];
        p[0] = fmaf(fi, w0.x, p[0]); p[1] = fmaf(fi, w0.y, p[1]);
        p[2] = fmaf(fi, w0.z, p[2]); p[3] = fmaf(fi, w0.w, p[3]);
        p[4] = fmaf(fi, w1.x, p[4]); p[5] = fmaf(fi, w1.y, p[5]);
        p[6] = fmaf(fi, w1.z, p[6]); p[7] = fmaf(fi, w1.w, p[7]);
        qq = fmaf(fi, br.x, qq);
        hr = fmaf(fi, br.y, hr);
    }
    uint4 pw;
    pw.x = (unsigned)f2bf(p[0]) | ((unsigned)f2bf(p[1]) << 16);
    pw.y = (unsigned)f2bf(p[2]) | ((unsigned)f2bf(p[3]) << 16);
    pw.z = (unsigned)f2bf(p[4]) | ((unsigned)f2bf(p[5]) << 16);
    pw.w = (unsigned)f2bf(p[6]) | ((unsigned)f2bf(p[7]) << 16);
    *(uint4*)(Pt + ((long long)n * H + j) * F_EDGE) = pw;
    q[(long long)n * H + j] = qq;
    aggseed[(long long)n * H + j] = hr + b[j];
}

// ---------------- CSR aggregation: one wave per node, NO atomics ------------
// lane = es*8 + j : es = edge slot (8 edges in flight), j = feature.
//   acc[j] += q[src][j] + sum_k ea[e][k]*Pt[src][j][k]   over this node's edges
// 3-step shfl_xor reduce over es, then one 32B store per node (layer 1) or
// fused ReLU->Wlast dot + one atomic per node into out[batch[n]] (layer 2).
template <bool FUSE_POOL>
__global__ __launch_bounds__(256) void edge_csr_kernel(
    const int* __restrict__ off, const int2* __restrict__ sorted,
    const float* __restrict__ ea, const unsigned short* __restrict__ Pt,
    const float* __restrict__ q, const float* __restrict__ seed,
    float* __restrict__ hout,
    const int* __restrict__ batch, const float* __restrict__ Wlast,
    float* __restrict__ out, int n_nodes) {
    int n = blockIdx.x * 4 + (threadIdx.x >> 6);
    if (n >= n_nodes) return;
    int lane = threadIdx.x & 63;
    int es = lane >> 3, j = lane & 7;

    int start = off[n], end = off[n + 1];
    float acc = 0.f;
    for (int k = start + es; k < end; k += 8) {
        int2 se = sorted[k];
        const float4* av = (const float4*)(ea + (long long)se.y * F_EDGE);
        float4 a0 = av[0], a1 = av[1];
        uint4 pw = *(const uint4*)(Pt + ((long long)se.x * H + j) * F_EDGE);
        float m = q[(long long)se.x * H + j];
        m = fmaf(a0.x, bflo(pw.x), m);
        m = fmaf(a0.y, bfhi(pw.x), m);
        m = fmaf(a0.z, bflo(pw.y), m);
        m = fmaf(a0.w, bfhi(pw.y), m);
        m = fmaf(a1.x, bflo(pw.z), m);
        m = fmaf(a1.y, bfhi(pw.z), m);
        m = fmaf(a1.z, bflo(pw.w), m);
        m = fmaf(a1.w, bfhi(pw.w), m);
        acc += m;
    }
    // reduce across the 8 edge slots (lanes with same j)
    acc += __shfl_xor(acc, 8);
    acc += __shfl_xor(acc, 16);
    acc += __shfl_xor(acc, 32);

    float h = seed[(long long)n * H + j] + acc;

    if (!FUSE_POOL) {
        if (es == 0) hout[(long long)n * H + j] = h;   // coalesced 32B/node
    } else {
        float c = fmaxf(h, 0.f) * Wlast[j];
        c += __shfl_xor(c, 1);
        c += __shfl_xor(c, 2);
        c += __shfl_xor(c, 4);
        if (lane == 0) unsafeAtomicAdd(&out[batch[n]], c);  // 1 atomic/node
    }
}

extern "C" void kernel_launch(void* const* d_in, const int* in_sizes, int n_in,
                              void* d_out, int out_size, void* d_ws, size_t ws_size,
                              hipStream_t stream) {
    const float* x     = (const float*)d_in[0];
    const int*   ei    = (const int*)d_in[1];
    const float* ea    = (const float*)d_in[2];
    const int*   batch = (const int*)d_in[3];
    const float* We1   = (const float*)d_in[4];
    const float* be1   = (const float*)d_in[5];
    const float* root1 = (const float*)d_in[6];
    const float* b1    = (const float*)d_in[7];
    const float* We2   = (const float*)d_in[8];
    const float* be2   = (const float*)d_in[9];
    const float* root2 = (const float*)d_in[10];
    const float* b2    = (const float*)d_in[11];
    const float* Wlast = (const float*)d_in[12];
    const float* blast = (const float*)d_in[13];
    float* out = (float*)d_out;

    int F_IN_rt = 16;
    int n_nodes = in_sizes[0] / F_IN_rt;
    int E = in_sizes[1] / 2;

    // workspace layout (16B aligned segments)
    char* w = (char*)d_ws;
    auto take = [&](size_t bytes) {
        char* p = w;
        w += (bytes + 15) & ~(size_t)15;
        return p;
    };
    unsigned short* Pt1 = (unsigned short*)take((size_t)n_nodes * H * F_EDGE * 2);
    unsigned short* Pt2 = (unsigned short*)take((size_t)n_nodes * H * F_EDGE * 2);
    float* q1    = (float*)take((size_t)n_nodes * H * 4);
    float* q2    = (float*)take((size_t)n_nodes * H * 4);
    float* h1    = (float*)take((size_t)n_nodes * H * 4);   // seed1, then h1 in place
    float* h2s   = (float*)take((size_t)n_nodes * H * 4);   // seed2 only
    int* deg     = (int*)take((size_t)n_nodes * 4);
    int* off     = (int*)take((size_t)(n_nodes + 1) * 4);
    int* cursor  = (int*)take((size_t)n_nodes * 4);
    int2* sorted = (int2*)take((size_t)E * 8);

    int nbn = (n_nodes + 255) / 256;
    int nbe = (E + 255) / 256;

    // CSR build
    zero_kernel<<<nbn, 256, 0, stream>>>(deg, n_nodes);
    degree_kernel<<<nbe, 256, 0, stream>>>(ei, deg, E);
    scan_kernel<<<1, 1024, 0, stream>>>(deg, off, cursor, n_nodes);
    scatter_kernel<<<nbe, 256, 0, stream>>>(ei, cursor, sorted, E);

    int nblocks = (n_nodes + 31) / 32;
    // prep1 also seeds out[g] = blast[0] (block 0)
    prep_kernel<16, false, true><<<nblocks, 256, 0, stream>>>(
        x, We1, be1, root1, b1, Pt1, q1, h1, n_nodes, out, blast, out_size);

    int ablk = (n_nodes + 3) / 4;   // 4 nodes (waves) per block
    edge_csr_kernel<false><<<ablk, 256, 0, stream>>>(
        off, sorted, ea, Pt1, q1, h1, h1, nullptr, nullptr, nullptr, n_nodes);

    prep_kernel<H, true, false><<<nblocks, 256, 0, stream>>>(
        h1, We2, be2, root2, b2, Pt2, q2, h2s, n_nodes, nullptr, nullptr, 0);

    // layer-2 aggregation with fused ReLU->Wlast dot + pooling
    edge_csr_kernel<true><<<ablk, 256, 0, stream>>>(
        off, sorted, ea, Pt2, q2, h2s, nullptr, batch, Wlast, out, n_nodes);
}